// Round 1
// baseline (3322.221 us; speedup 1.0000x reference)
//
#include <hip/hip_runtime.h>

#define IN_DIM 128
#define HID_DIM 128
#define OUT_DIM 64

// ---------------------------------------------------------------------------
// Edge-parallel scatter-add: agg[dst[e]][:] += x[src[e]][:], optional degree.
// 32 lanes per edge, float4 gathers (coalesced 512B per row).
// ---------------------------------------------------------------------------
template<int D, bool COUNT_DEG>
__global__ void scatter_add_kernel(const float* __restrict__ x,
                                   const int* __restrict__ src,
                                   const int* __restrict__ dst,
                                   float* __restrict__ agg,
                                   float* __restrict__ deg,
                                   int E) {
    constexpr int V = D / 4;  // float4 chunks per row (32 for D=128)
    int tid = blockIdx.x * blockDim.x + threadIdx.x;
    int e  = tid >> 5;        // V == 32
    int d4 = tid & 31;
    if (e >= E) return;
    int s = src[e];
    int t = dst[e];
    const float4 v = *reinterpret_cast<const float4*>(&x[(size_t)s * D + d4 * 4]);
    float* a = &agg[(size_t)t * D + d4 * 4];
    atomicAdd(a + 0, v.x);
    atomicAdd(a + 1, v.y);
    atomicAdd(a + 2, v.z);
    atomicAdd(a + 3, v.w);
    if (COUNT_DEG && d4 == 0) atomicAdd(&deg[t], 1.0f);
    (void)V;
}

// ---------------------------------------------------------------------------
// Fused SAGE linear: out[n][j] = act( x[n]·Wself[:,j] + (agg[n]/max(deg,1))·Wneigh[:,j] + b[j] )
// Both weight matrices staged in LDS; per-node input rows staged in LDS and
// broadcast across lanes. 256 threads, each thread owns one output column j
// for one of 256/DOUT nodes per iteration.
// ---------------------------------------------------------------------------
template<int DIN, int DOUT, bool RELU>
__global__ void sage_gemm_kernel(const float* __restrict__ x,
                                 const float* __restrict__ agg,
                                 const float* __restrict__ deg,
                                 const float* __restrict__ Wself,
                                 const float* __restrict__ Wneigh,
                                 const float* __restrict__ bias,
                                 float* __restrict__ out,
                                 int N) {
    constexpr int NPB = 256 / DOUT;  // nodes per iteration (2 for 128, 4 for 64)
    __shared__ float sWs[DIN][DOUT];
    __shared__ float sWn[DIN][DOUT];
    __shared__ float sX[NPB][DIN];
    __shared__ float sH[NPB][DIN];

    for (int i = threadIdx.x; i < DIN * DOUT; i += blockDim.x) {
        sWs[i / DOUT][i % DOUT] = Wself[i];
        sWn[i / DOUT][i % DOUT] = Wneigh[i];
    }
    const int j   = threadIdx.x % DOUT;
    const int sub = threadIdx.x / DOUT;
    const float bj = bias[j];

    for (int n0 = blockIdx.x * NPB; n0 < N; n0 += gridDim.x * NPB) {
        __syncthreads();
        for (int i = threadIdx.x; i < NPB * DIN; i += blockDim.x) {
            int nn = i / DIN, d = i % DIN;
            int n = n0 + nn;
            if (n < N) {
                sX[nn][d] = x[(size_t)n * DIN + d];
                float r = 1.0f / fmaxf(deg[n], 1.0f);
                sH[nn][d] = agg[(size_t)n * DIN + d] * r;
            }
        }
        __syncthreads();
        int n = n0 + sub;
        if (n < N) {
            float acc = bj;
            #pragma unroll 8
            for (int d = 0; d < DIN; ++d) {
                acc += sX[sub][d] * sWs[d][j] + sH[sub][d] * sWn[d][j];
            }
            out[(size_t)n * DOUT + j] = RELU ? fmaxf(acc, 0.0f) : acc;
        }
    }
}

// ---------------------------------------------------------------------------
// Edge dot: out[e] = sum_d h[src[e]][d] * h[dst[e]][d], D=64.
// 16 lanes per edge, float4 loads, shfl_xor reduce within 16-lane groups.
// Handles both positive (first E) and negative (second E) edge sets.
// ---------------------------------------------------------------------------
__global__ void edge_dot_kernel(const float* __restrict__ h,
                                const int* __restrict__ src,
                                const int* __restrict__ dst,
                                const int* __restrict__ nsrc,
                                const int* __restrict__ ndst,
                                float* __restrict__ out,
                                int E) {
    int tid = blockIdx.x * blockDim.x + threadIdx.x;
    int eg = tid >> 4;
    int l  = tid & 15;
    if (eg >= 2 * E) return;
    int s, t;
    if (eg < E) { s = src[eg];      t = dst[eg]; }
    else        { s = nsrc[eg - E]; t = ndst[eg - E]; }
    const float4 a = *reinterpret_cast<const float4*>(&h[(size_t)s * OUT_DIM + l * 4]);
    const float4 b = *reinterpret_cast<const float4*>(&h[(size_t)t * OUT_DIM + l * 4]);
    float v = a.x * b.x + a.y * b.y + a.z * b.z + a.w * b.w;
    v += __shfl_xor(v, 8, 16);
    v += __shfl_xor(v, 4, 16);
    v += __shfl_xor(v, 2, 16);
    v += __shfl_xor(v, 1, 16);
    if (l == 0) out[eg] = v;
}

extern "C" void kernel_launch(void* const* d_in, const int* in_sizes, int n_in,
                              void* d_out, int out_size, void* d_ws, size_t ws_size,
                              hipStream_t stream) {
    const float* feat = (const float*)d_in[0];
    const float* Ws1  = (const float*)d_in[1];
    const float* Wn1  = (const float*)d_in[2];
    const float* b1   = (const float*)d_in[3];
    const float* Ws2  = (const float*)d_in[4];
    const float* Wn2  = (const float*)d_in[5];
    const float* b2   = (const float*)d_in[6];
    const int* src  = (const int*)d_in[7];
    const int* dst  = (const int*)d_in[8];
    const int* nsrc = (const int*)d_in[9];
    const int* ndst = (const int*)d_in[10];
    const int E = in_sizes[7];
    const int N = in_sizes[0] / IN_DIM;

    float* ws   = (float*)d_ws;
    float* deg  = ws;                          // N
    float* agg1 = deg  + N;                    // N*128
    float* h1   = agg1 + (size_t)N * HID_DIM;  // N*128
    float* agg2 = h1   + (size_t)N * HID_DIM;  // N*128
    float* h2   = agg2 + (size_t)N * HID_DIM;  // N*64

    // Zero accumulators (deg+agg1 contiguous; agg2 separate).
    hipMemsetAsync(deg,  0, sizeof(float) * ((size_t)N * (1 + HID_DIM)), stream);
    hipMemsetAsync(agg2, 0, sizeof(float) * ((size_t)N * HID_DIM), stream);

    // Layer 1 aggregation (+degree)
    {
        int total = E * 32;
        scatter_add_kernel<IN_DIM, true><<<(total + 255) / 256, 256, 0, stream>>>(
            feat, src, dst, agg1, deg, E);
    }
    // Layer 1 linear + ReLU
    sage_gemm_kernel<IN_DIM, HID_DIM, true><<<256, 256, 0, stream>>>(
        feat, agg1, deg, Ws1, Wn1, b1, h1, N);

    // Layer 2 aggregation
    {
        int total = E * 32;
        scatter_add_kernel<HID_DIM, false><<<(total + 255) / 256, 256, 0, stream>>>(
            h1, src, dst, agg2, nullptr, E);
    }
    // Layer 2 linear
    sage_gemm_kernel<HID_DIM, OUT_DIM, false><<<512, 256, 0, stream>>>(
        h1, agg2, deg, Ws2, Wn2, b2, h2, N);

    // Edge dots (positive then negative), concatenated into d_out.
    {
        int total = 2 * E * 16;
        edge_dot_kernel<<<(total + 255) / 256, 256, 0, stream>>>(
            h2, src, dst, nsrc, ndst, (float*)d_out, E);
    }
}

// Round 2
// 433.165 us; speedup vs baseline: 7.6696x; 7.6696x over previous
//
#include <hip/hip_runtime.h>

#define IN_DIM 128
#define HID_DIM 128
#define OUT_DIM 64

// ===========================================================================
// CSR build: histogram -> 3-kernel exclusive scan -> fill column (src) array
// ===========================================================================
__global__ void hist_kernel(const int* __restrict__ dst, int* __restrict__ cnt, int E) {
    int e = blockIdx.x * blockDim.x + threadIdx.x;
    if (e < E) atomicAdd(&cnt[dst[e]], 1);
}

__global__ void block_sums_kernel(const int* __restrict__ cnt, int* __restrict__ partial, int N) {
    __shared__ int s[256];
    int i = blockIdx.x * 256 + threadIdx.x;
    s[threadIdx.x] = (i < N) ? cnt[i] : 0;
    __syncthreads();
    for (int o = 128; o > 0; o >>= 1) {
        if (threadIdx.x < o) s[threadIdx.x] += s[threadIdx.x + o];
        __syncthreads();
    }
    if (threadIdx.x == 0) partial[blockIdx.x] = s[0];
}

__global__ void scan_partials_kernel(int* __restrict__ partial, int nB) {
    // single block; nB <= 256
    __shared__ int s[256];
    int v = (threadIdx.x < nB) ? partial[threadIdx.x] : 0;
    s[threadIdx.x] = v;
    __syncthreads();
    for (int o = 1; o < 256; o <<= 1) {
        int t = (threadIdx.x >= o) ? s[threadIdx.x - o] : 0;
        __syncthreads();
        s[threadIdx.x] += t;
        __syncthreads();
    }
    if (threadIdx.x < nB) partial[threadIdx.x] = s[threadIdx.x] - v;  // exclusive
}

__global__ void scan_chunks_kernel(const int* __restrict__ cnt, const int* __restrict__ partial,
                                   int* __restrict__ row_ptr, int N) {
    __shared__ int s[256];
    int i = blockIdx.x * 256 + threadIdx.x;
    int v = (i < N) ? cnt[i] : 0;
    s[threadIdx.x] = v;
    __syncthreads();
    for (int o = 1; o < 256; o <<= 1) {
        int t = (threadIdx.x >= o) ? s[threadIdx.x - o] : 0;
        __syncthreads();
        s[threadIdx.x] += t;
        __syncthreads();
    }
    int incl = s[threadIdx.x];
    int base = partial[blockIdx.x];
    if (i < N) row_ptr[i] = base + incl - v;
    if (i == N - 1) row_ptr[N] = base + incl;
}

__global__ void fill_csr_kernel(const int* __restrict__ src, const int* __restrict__ dst,
                                const int* __restrict__ row_ptr, int* __restrict__ fill,
                                int* __restrict__ col_src, int E) {
    int e = blockIdx.x * blockDim.x + threadIdx.x;
    if (e >= E) return;
    int t = dst[e];
    int p = row_ptr[t] + atomicAdd(&fill[t], 1);
    col_src[p] = src[e];
}

// ===========================================================================
// Dual GEMM: hs[n] = x[n] @ Wself + b ; t[n] = x[n] @ Wneigh
// Both weight matrices in LDS (shared across grid-stride loop), X tile in LDS.
// Thread owns 4 output columns (j0..j0+3) x 4 nodes -> 32 FMAs per LDS triple.
// ===========================================================================
template<int DIN, int DOUT>
__global__ __launch_bounds__(256) void dual_gemm_kernel(
        const float* __restrict__ x,
        const float* __restrict__ Wself,
        const float* __restrict__ Wneigh,
        const float* __restrict__ bias,
        float* __restrict__ hs,
        float* __restrict__ t,
        int N) {
    constexpr int JG    = DOUT / 4;      // j-groups of 4 columns (32 or 16)
    constexpr int SLOTS = 256 / JG;      // node slots (8 or 16)
    constexpr int NN    = 4;             // nodes per slot
    constexpr int NPB   = SLOTS * NN;    // nodes per block-iter (32 or 64)

    __shared__ float sWs[DIN][DOUT];
    __shared__ float sWn[DIN][DOUT];
    __shared__ float sX[NPB][DIN + 4];   // +4 pad: distinct banks for row-broadcasts

    for (int i = threadIdx.x; i < DIN * DOUT / 4; i += 256) {
        *(float4*)&sWs[0][i * 4] = *(const float4*)&Wself[i * 4];
        *(float4*)&sWn[0][i * 4] = *(const float4*)&Wneigh[i * 4];
    }

    const int jg   = threadIdx.x % JG;
    const int slot = threadIdx.x / JG;
    const int j0   = jg * 4;
    const float4 bj4 = *(const float4*)&bias[j0];

    for (int n0 = blockIdx.x * NPB; n0 < N; n0 += gridDim.x * NPB) {
        __syncthreads();
        for (int i = threadIdx.x; i < NPB * DIN / 4; i += 256) {
            int nn = i / (DIN / 4), dd = i % (DIN / 4);
            int n = n0 + nn;
            float4 v = {0, 0, 0, 0};
            if (n < N) v = *(const float4*)&x[(size_t)n * DIN + dd * 4];
            *(float4*)&sX[nn][dd * 4] = v;
        }
        __syncthreads();

        const int nbase = slot * NN;
        float4 accs[NN], accn[NN];
        #pragma unroll
        for (int k = 0; k < NN; ++k) {
            accs[k] = bj4;
            accn[k] = {0, 0, 0, 0};
        }
        #pragma unroll 4
        for (int d = 0; d < DIN; ++d) {
            const float4 ws = *(const float4*)&sWs[d][j0];
            const float4 wn = *(const float4*)&sWn[d][j0];
            #pragma unroll
            for (int k = 0; k < NN; ++k) {
                const float xv = sX[nbase + k][d];
                accs[k].x += xv * ws.x; accs[k].y += xv * ws.y;
                accs[k].z += xv * ws.z; accs[k].w += xv * ws.w;
                accn[k].x += xv * wn.x; accn[k].y += xv * wn.y;
                accn[k].z += xv * wn.z; accn[k].w += xv * wn.w;
            }
        }
        #pragma unroll
        for (int k = 0; k < NN; ++k) {
            int n = n0 + nbase + k;
            if (n < N) {
                *(float4*)&hs[(size_t)n * DOUT + j0] = accs[k];
                *(float4*)&t [(size_t)n * DOUT + j0] = accn[k];
            }
        }
    }
}

// ===========================================================================
// Gather-mean + self-path epilogue: out[v] = act(base[v] + mean_{s in N(v)} t[s])
// One 64-lane wave per node; coalesced row reads; 4-edge unroll for MLP.
// ===========================================================================
template<int D, bool RELU>
__global__ void gather_mean_kernel(const float* __restrict__ t,
                                   const float* __restrict__ base,
                                   const int* __restrict__ row_ptr,
                                   const int* __restrict__ col_src,
                                   float* __restrict__ out, int N) {
    int node = (blockIdx.x * blockDim.x + threadIdx.x) >> 6;
    int lane = threadIdx.x & 63;
    if (node >= N) return;
    const int beg = row_ptr[node], end = row_ptr[node + 1];
    const float rdeg = 1.0f / fmaxf((float)(end - beg), 1.0f);

    if constexpr (D == 128) {
        float ax0 = 0, ay0 = 0, ax1 = 0, ay1 = 0, ax2 = 0, ay2 = 0, ax3 = 0, ay3 = 0;
        int i = beg;
        for (; i + 4 <= end; i += 4) {
            int s0 = col_src[i], s1 = col_src[i + 1], s2 = col_src[i + 2], s3 = col_src[i + 3];
            float2 v0 = *(const float2*)&t[(size_t)s0 * D + lane * 2];
            float2 v1 = *(const float2*)&t[(size_t)s1 * D + lane * 2];
            float2 v2 = *(const float2*)&t[(size_t)s2 * D + lane * 2];
            float2 v3 = *(const float2*)&t[(size_t)s3 * D + lane * 2];
            ax0 += v0.x; ay0 += v0.y;
            ax1 += v1.x; ay1 += v1.y;
            ax2 += v2.x; ay2 += v2.y;
            ax3 += v3.x; ay3 += v3.y;
        }
        for (; i < end; ++i) {
            int s = col_src[i];
            float2 v = *(const float2*)&t[(size_t)s * D + lane * 2];
            ax0 += v.x; ay0 += v.y;
        }
        float ax = (ax0 + ax1) + (ax2 + ax3);
        float ay = (ay0 + ay1) + (ay2 + ay3);
        float2 b = *(const float2*)&base[(size_t)node * D + lane * 2];
        float ox = b.x + ax * rdeg;
        float oy = b.y + ay * rdeg;
        if (RELU) { ox = fmaxf(ox, 0.0f); oy = fmaxf(oy, 0.0f); }
        float2 o = {ox, oy};
        *(float2*)&out[(size_t)node * D + lane * 2] = o;
    } else {
        float a0 = 0, a1 = 0, a2 = 0, a3 = 0;
        int i = beg;
        for (; i + 4 <= end; i += 4) {
            int s0 = col_src[i], s1 = col_src[i + 1], s2 = col_src[i + 2], s3 = col_src[i + 3];
            a0 += t[(size_t)s0 * D + lane];
            a1 += t[(size_t)s1 * D + lane];
            a2 += t[(size_t)s2 * D + lane];
            a3 += t[(size_t)s3 * D + lane];
        }
        for (; i < end; ++i) a0 += t[(size_t)col_src[i] * D + lane];
        float a = (a0 + a1) + (a2 + a3);
        float o = base[(size_t)node * D + lane] + a * rdeg;
        if (RELU) o = fmaxf(o, 0.0f);
        out[(size_t)node * D + lane] = o;
    }
}

// ===========================================================================
// Edge dot: out[e] = h[src[e]] . h[dst[e]], D=64; 16 lanes/edge, float4 loads.
// ===========================================================================
__global__ void edge_dot_kernel(const float* __restrict__ h,
                                const int* __restrict__ src,
                                const int* __restrict__ dst,
                                const int* __restrict__ nsrc,
                                const int* __restrict__ ndst,
                                float* __restrict__ out,
                                int E) {
    int tid = blockIdx.x * blockDim.x + threadIdx.x;
    int eg = tid >> 4;
    int l  = tid & 15;
    if (eg >= 2 * E) return;
    int s, t;
    if (eg < E) { s = src[eg];      t = dst[eg]; }
    else        { s = nsrc[eg - E]; t = ndst[eg - E]; }
    const float4 a = *reinterpret_cast<const float4*>(&h[(size_t)s * OUT_DIM + l * 4]);
    const float4 b = *reinterpret_cast<const float4*>(&h[(size_t)t * OUT_DIM + l * 4]);
    float v = a.x * b.x + a.y * b.y + a.z * b.z + a.w * b.w;
    v += __shfl_xor(v, 8, 16);
    v += __shfl_xor(v, 4, 16);
    v += __shfl_xor(v, 2, 16);
    v += __shfl_xor(v, 1, 16);
    if (l == 0) out[eg] = v;
}

extern "C" void kernel_launch(void* const* d_in, const int* in_sizes, int n_in,
                              void* d_out, int out_size, void* d_ws, size_t ws_size,
                              hipStream_t stream) {
    const float* feat = (const float*)d_in[0];
    const float* Ws1  = (const float*)d_in[1];
    const float* Wn1  = (const float*)d_in[2];
    const float* b1   = (const float*)d_in[3];
    const float* Ws2  = (const float*)d_in[4];
    const float* Wn2  = (const float*)d_in[5];
    const float* b2   = (const float*)d_in[6];
    const int* src  = (const int*)d_in[7];
    const int* dst  = (const int*)d_in[8];
    const int* nsrc = (const int*)d_in[9];
    const int* ndst = (const int*)d_in[10];
    const int E = in_sizes[7];
    const int N = in_sizes[0] / IN_DIM;
    const int NB = (N + 255) / 256;  // scan chunks (<= 256 required)

    // ---- workspace layout ----
    int* wsi     = (int*)d_ws;
    int* cnt     = wsi;                  // N
    int* fill    = cnt + N;              // N  (cnt+fill zeroed by one memset)
    int* row_ptr = fill + N;             // N+1
    int* partial = row_ptr + N + 1;      // NB
    int* col_src = partial + 256;        // E
    size_t int_count = (size_t)(3 * N + 1 + 256) + (size_t)E;
    int_count = (int_count + 3) & ~(size_t)3;  // 16B align for floats
    float* A = (float*)(wsi + int_count);          // t1 / t2      [N*128]
    float* B = A + (size_t)N * HID_DIM;            // hs1 / hs2    [N*128]
    float* C = B + (size_t)N * HID_DIM;            // h1, then h2  [N*128]

    // ---- CSR build (edge list shared by both layers) ----
    hipMemsetAsync(cnt, 0, sizeof(int) * 2 * (size_t)N, stream);
    hist_kernel<<<(E + 255) / 256, 256, 0, stream>>>(dst, cnt, E);
    block_sums_kernel<<<NB, 256, 0, stream>>>(cnt, partial, N);
    scan_partials_kernel<<<1, 256, 0, stream>>>(partial, NB);
    scan_chunks_kernel<<<NB, 256, 0, stream>>>(cnt, partial, row_ptr, N);
    fill_csr_kernel<<<(E + 255) / 256, 256, 0, stream>>>(src, dst, row_ptr, fill, col_src, E);

    // ---- Layer 1: hs1 = feat@Ws1+b1, t1 = feat@Wn1; h1 = relu(hs1 + mean(t1)) ----
    dual_gemm_kernel<IN_DIM, HID_DIM><<<256, 256, 0, stream>>>(
        feat, Ws1, Wn1, b1, B, A, N);
    gather_mean_kernel<HID_DIM, true><<<(N * 64 + 255) / 256, 256, 0, stream>>>(
        A, B, row_ptr, col_src, C, N);

    // ---- Layer 2: hs2 = h1@Ws2+b2, t2 = h1@Wn2; h2 = hs2 + mean(t2) ----
    dual_gemm_kernel<HID_DIM, OUT_DIM><<<256, 256, 0, stream>>>(
        C, Ws2, Wn2, b2, B, A, N);
    gather_mean_kernel<OUT_DIM, false><<<(N * 64 + 255) / 256, 256, 0, stream>>>(
        A, B, row_ptr, col_src, C, N);  // h2 overwrites h1 (no longer needed)

    // ---- Edge dots (positive then negative) ----
    {
        int total = 2 * E * 16;
        edge_dot_kernel<<<(total + 255) / 256, 256, 0, stream>>>(
            C, src, dst, nsrc, ndst, (float*)d_out, E);
    }
}

// Round 3
// 334.818 us; speedup vs baseline: 9.9225x; 1.2937x over previous
//
#include <hip/hip_runtime.h>

#define IN_DIM 128
#define HID_DIM 128
#define OUT_DIM 64

// ---- bf16 helpers (storage-only; all math in fp32) ----
__device__ inline float bflo(unsigned int u) { return __uint_as_float(u << 16); }
__device__ inline float bfhi(unsigned int u) { return __uint_as_float(u & 0xffff0000u); }
__device__ inline unsigned short f2bf(float f) {
    unsigned int b = __float_as_uint(f);
    return (unsigned short)((b + 0x7FFFu + ((b >> 16) & 1u)) >> 16);  // RNE
}
__device__ inline unsigned int pack2(float a, float b) {
    return (unsigned int)f2bf(a) | ((unsigned int)f2bf(b) << 16);
}

// ===========================================================================
// CSR build: histogram -> 3-kernel exclusive scan -> fill column (src) array
// ===========================================================================
__global__ void hist_kernel(const int* __restrict__ dst, int* __restrict__ cnt, int E) {
    int e = blockIdx.x * blockDim.x + threadIdx.x;
    if (e < E) atomicAdd(&cnt[dst[e]], 1);
}

__global__ void block_sums_kernel(const int* __restrict__ cnt, int* __restrict__ partial, int N) {
    __shared__ int s[256];
    int i = blockIdx.x * 256 + threadIdx.x;
    s[threadIdx.x] = (i < N) ? cnt[i] : 0;
    __syncthreads();
    for (int o = 128; o > 0; o >>= 1) {
        if (threadIdx.x < o) s[threadIdx.x] += s[threadIdx.x + o];
        __syncthreads();
    }
    if (threadIdx.x == 0) partial[blockIdx.x] = s[0];
}

__global__ void scan_partials_kernel(int* __restrict__ partial, int nB) {
    __shared__ int s[256];
    int v = (threadIdx.x < nB) ? partial[threadIdx.x] : 0;
    s[threadIdx.x] = v;
    __syncthreads();
    for (int o = 1; o < 256; o <<= 1) {
        int t = (threadIdx.x >= o) ? s[threadIdx.x - o] : 0;
        __syncthreads();
        s[threadIdx.x] += t;
        __syncthreads();
    }
    if (threadIdx.x < nB) partial[threadIdx.x] = s[threadIdx.x] - v;  // exclusive
}

__global__ void scan_chunks_kernel(const int* __restrict__ cnt, const int* __restrict__ partial,
                                   int* __restrict__ row_ptr, int N) {
    __shared__ int s[256];
    int i = blockIdx.x * 256 + threadIdx.x;
    int v = (i < N) ? cnt[i] : 0;
    s[threadIdx.x] = v;
    __syncthreads();
    for (int o = 1; o < 256; o <<= 1) {
        int t = (threadIdx.x >= o) ? s[threadIdx.x - o] : 0;
        __syncthreads();
        s[threadIdx.x] += t;
        __syncthreads();
    }
    int incl = s[threadIdx.x];
    int base = partial[blockIdx.x];
    if (i < N) row_ptr[i] = base + incl - v;
    if (i == N - 1) row_ptr[N] = base + incl;
}

__global__ void fill_csr_kernel(const int* __restrict__ src, const int* __restrict__ dst,
                                const int* __restrict__ row_ptr, int* __restrict__ fill,
                                int* __restrict__ col_src, int E) {
    int e = blockIdx.x * blockDim.x + threadIdx.x;
    if (e >= E) return;
    int t = dst[e];
    int p = row_ptr[t] + atomicAdd(&fill[t], 1);
    col_src[p] = src[e];
}

// ===========================================================================
// Dual GEMM: hs[n] = x[n]@Wself + b (fp32) ; t[n] = x[n]@Wneigh (bf16 packed)
// ===========================================================================
template<int DIN, int DOUT>
__global__ __launch_bounds__(256) void dual_gemm_kernel(
        const float* __restrict__ x,
        const float* __restrict__ Wself,
        const float* __restrict__ Wneigh,
        const float* __restrict__ bias,
        float* __restrict__ hs,
        unsigned short* __restrict__ t,
        int N) {
    constexpr int JG    = DOUT / 4;
    constexpr int SLOTS = 256 / JG;
    constexpr int NN    = 4;
    constexpr int NPB   = SLOTS * NN;

    __shared__ float sWs[DIN][DOUT];
    __shared__ float sWn[DIN][DOUT];
    __shared__ float sX[NPB][DIN + 4];

    for (int i = threadIdx.x; i < DIN * DOUT / 4; i += 256) {
        *(float4*)&sWs[0][i * 4] = *(const float4*)&Wself[i * 4];
        *(float4*)&sWn[0][i * 4] = *(const float4*)&Wneigh[i * 4];
    }

    const int jg   = threadIdx.x % JG;
    const int slot = threadIdx.x / JG;
    const int j0   = jg * 4;
    const float4 bj4 = *(const float4*)&bias[j0];

    for (int n0 = blockIdx.x * NPB; n0 < N; n0 += gridDim.x * NPB) {
        __syncthreads();
        for (int i = threadIdx.x; i < NPB * DIN / 4; i += 256) {
            int nn = i / (DIN / 4), dd = i % (DIN / 4);
            int n = n0 + nn;
            float4 v = {0, 0, 0, 0};
            if (n < N) v = *(const float4*)&x[(size_t)n * DIN + dd * 4];
            *(float4*)&sX[nn][dd * 4] = v;
        }
        __syncthreads();

        const int nbase = slot * NN;
        float4 accs[NN], accn[NN];
        #pragma unroll
        for (int k = 0; k < NN; ++k) {
            accs[k] = bj4;
            accn[k] = {0, 0, 0, 0};
        }
        #pragma unroll 4
        for (int d = 0; d < DIN; ++d) {
            const float4 ws = *(const float4*)&sWs[d][j0];
            const float4 wn = *(const float4*)&sWn[d][j0];
            #pragma unroll
            for (int k = 0; k < NN; ++k) {
                const float xv = sX[nbase + k][d];
                accs[k].x += xv * ws.x; accs[k].y += xv * ws.y;
                accs[k].z += xv * ws.z; accs[k].w += xv * ws.w;
                accn[k].x += xv * wn.x; accn[k].y += xv * wn.y;
                accn[k].z += xv * wn.z; accn[k].w += xv * wn.w;
            }
        }
        #pragma unroll
        for (int k = 0; k < NN; ++k) {
            int n = n0 + nbase + k;
            if (n < N) {
                *(float4*)&hs[(size_t)n * DOUT + j0] = accs[k];
                uint2 uu;
                uu.x = pack2(accn[k].x, accn[k].y);
                uu.y = pack2(accn[k].z, accn[k].w);
                *(uint2*)&t[(size_t)n * DOUT + j0] = uu;
            }
        }
    }
}

// ===========================================================================
// Gather-mean layer 1 (D=128): one 64-lane wave per node, 4B (2 bf16) / lane.
// out (fp32) = relu(base + mean t[neighbors])
// ===========================================================================
__global__ void gather_mean128_kernel(const unsigned short* __restrict__ t,
                                      const float* __restrict__ base,
                                      const int* __restrict__ row_ptr,
                                      const int* __restrict__ col_src,
                                      float* __restrict__ out, int N) {
    int node = (blockIdx.x * blockDim.x + threadIdx.x) >> 6;
    int lane = threadIdx.x & 63;
    if (node >= N) return;
    const int beg = row_ptr[node], end = row_ptr[node + 1];
    const float rdeg = 1.0f / fmaxf((float)(end - beg), 1.0f);
    const int off = lane * 2;

    float a0x = 0, a0y = 0, a1x = 0, a1y = 0, a2x = 0, a2y = 0, a3x = 0, a3y = 0;
    int i = beg;
    for (; i + 4 <= end; i += 4) {
        int s0 = col_src[i], s1 = col_src[i + 1], s2 = col_src[i + 2], s3 = col_src[i + 3];
        unsigned int u0 = *(const unsigned int*)&t[(size_t)s0 * 128 + off];
        unsigned int u1 = *(const unsigned int*)&t[(size_t)s1 * 128 + off];
        unsigned int u2 = *(const unsigned int*)&t[(size_t)s2 * 128 + off];
        unsigned int u3 = *(const unsigned int*)&t[(size_t)s3 * 128 + off];
        a0x += bflo(u0); a0y += bfhi(u0);
        a1x += bflo(u1); a1y += bfhi(u1);
        a2x += bflo(u2); a2y += bfhi(u2);
        a3x += bflo(u3); a3y += bfhi(u3);
    }
    for (; i < end; ++i) {
        unsigned int u = *(const unsigned int*)&t[(size_t)col_src[i] * 128 + off];
        a0x += bflo(u); a0y += bfhi(u);
    }
    float ax = (a0x + a1x) + (a2x + a3x);
    float ay = (a0y + a1y) + (a2y + a3y);
    float2 b = *(const float2*)&base[(size_t)node * 128 + off];
    float ox = fmaxf(b.x + ax * rdeg, 0.0f);
    float oy = fmaxf(b.y + ay * rdeg, 0.0f);
    float2 o = {ox, oy};
    *(float2*)&out[(size_t)node * 128 + off] = o;
}

// ===========================================================================
// Gather-mean layer 2 (D=64): 32 lanes per node (2 nodes/wave), bf16 out.
// out (bf16) = base + mean t[neighbors]
// ===========================================================================
__global__ void gather_mean64_kernel(const unsigned short* __restrict__ t,
                                     const float* __restrict__ base,
                                     const int* __restrict__ row_ptr,
                                     const int* __restrict__ col_src,
                                     unsigned short* __restrict__ out, int N) {
    int tid  = blockIdx.x * blockDim.x + threadIdx.x;
    int node = (tid >> 6) * 2 + ((tid >> 5) & 1);
    int m    = tid & 31;
    if (node >= N) return;
    const int beg = row_ptr[node], end = row_ptr[node + 1];
    const float rdeg = 1.0f / fmaxf((float)(end - beg), 1.0f);
    const int off = m * 2;

    float a0x = 0, a0y = 0, a1x = 0, a1y = 0, a2x = 0, a2y = 0, a3x = 0, a3y = 0;
    int i = beg;
    for (; i + 4 <= end; i += 4) {
        int s0 = col_src[i], s1 = col_src[i + 1], s2 = col_src[i + 2], s3 = col_src[i + 3];
        unsigned int u0 = *(const unsigned int*)&t[(size_t)s0 * 64 + off];
        unsigned int u1 = *(const unsigned int*)&t[(size_t)s1 * 64 + off];
        unsigned int u2 = *(const unsigned int*)&t[(size_t)s2 * 64 + off];
        unsigned int u3 = *(const unsigned int*)&t[(size_t)s3 * 64 + off];
        a0x += bflo(u0); a0y += bfhi(u0);
        a1x += bflo(u1); a1y += bfhi(u1);
        a2x += bflo(u2); a2y += bfhi(u2);
        a3x += bflo(u3); a3y += bfhi(u3);
    }
    for (; i < end; ++i) {
        unsigned int u = *(const unsigned int*)&t[(size_t)col_src[i] * 64 + off];
        a0x += bflo(u); a0y += bfhi(u);
    }
    float ax = (a0x + a1x) + (a2x + a3x);
    float ay = (a0y + a1y) + (a2y + a3y);
    float2 b = *(const float2*)&base[(size_t)node * 64 + off];
    float ox = b.x + ax * rdeg;
    float oy = b.y + ay * rdeg;
    *(unsigned int*)&out[(size_t)node * 64 + off] = pack2(ox, oy);
}

// ===========================================================================
// Edge dot on bf16 h (D=64, 128B rows): 8 lanes/edge, uint4 (8 bf16) loads.
// ===========================================================================
__global__ void edge_dot_kernel(const unsigned short* __restrict__ h,
                                const int* __restrict__ src,
                                const int* __restrict__ dst,
                                const int* __restrict__ nsrc,
                                const int* __restrict__ ndst,
                                float* __restrict__ out,
                                int E) {
    int tid = blockIdx.x * blockDim.x + threadIdx.x;
    int eg = tid >> 3;
    int l  = tid & 7;
    if (eg >= 2 * E) return;
    int s, t;
    if (eg < E) { s = src[eg];      t = dst[eg]; }
    else        { s = nsrc[eg - E]; t = ndst[eg - E]; }
    const uint4 a = *reinterpret_cast<const uint4*>(&h[(size_t)s * OUT_DIM + l * 8]);
    const uint4 b = *reinterpret_cast<const uint4*>(&h[(size_t)t * OUT_DIM + l * 8]);
    float v = bflo(a.x) * bflo(b.x) + bfhi(a.x) * bfhi(b.x)
            + bflo(a.y) * bflo(b.y) + bfhi(a.y) * bfhi(b.y)
            + bflo(a.z) * bflo(b.z) + bfhi(a.z) * bfhi(b.z)
            + bflo(a.w) * bflo(b.w) + bfhi(a.w) * bfhi(b.w);
    v += __shfl_xor(v, 4, 8);
    v += __shfl_xor(v, 2, 8);
    v += __shfl_xor(v, 1, 8);
    if (l == 0) out[eg] = v;
}

extern "C" void kernel_launch(void* const* d_in, const int* in_sizes, int n_in,
                              void* d_out, int out_size, void* d_ws, size_t ws_size,
                              hipStream_t stream) {
    const float* feat = (const float*)d_in[0];
    const float* Ws1  = (const float*)d_in[1];
    const float* Wn1  = (const float*)d_in[2];
    const float* b1   = (const float*)d_in[3];
    const float* Ws2  = (const float*)d_in[4];
    const float* Wn2  = (const float*)d_in[5];
    const float* b2   = (const float*)d_in[6];
    const int* src  = (const int*)d_in[7];
    const int* dst  = (const int*)d_in[8];
    const int* nsrc = (const int*)d_in[9];
    const int* ndst = (const int*)d_in[10];
    const int E = in_sizes[7];
    const int N = in_sizes[0] / IN_DIM;
    const int NB = (N + 255) / 256;

    // ---- workspace layout ----
    int* wsi     = (int*)d_ws;
    int* cnt     = wsi;                  // N
    int* fill    = cnt + N;              // N
    int* row_ptr = fill + N;             // N+1
    int* partial = row_ptr + N + 1;      // 256
    int* col_src = partial + 256;        // E
    size_t int_count = (size_t)(3 * N + 1 + 256) + (size_t)E;
    int_count = (int_count + 3) & ~(size_t)3;
    unsigned short* t_bf = (unsigned short*)(wsi + int_count);       // N*128 bf16 (t1 / t2)
    float* hs = (float*)(t_bf + (size_t)N * HID_DIM);                // N*128 fp32 (hs1 / hs2)
    float* h1 = hs + (size_t)N * HID_DIM;                            // N*128 fp32
    unsigned short* h2_bf = (unsigned short*)(h1 + (size_t)N * HID_DIM);  // N*64 bf16

    // ---- CSR build ----
    hipMemsetAsync(cnt, 0, sizeof(int) * 2 * (size_t)N, stream);
    hist_kernel<<<(E + 255) / 256, 256, 0, stream>>>(dst, cnt, E);
    block_sums_kernel<<<NB, 256, 0, stream>>>(cnt, partial, N);
    scan_partials_kernel<<<1, 256, 0, stream>>>(partial, NB);
    scan_chunks_kernel<<<NB, 256, 0, stream>>>(cnt, partial, row_ptr, N);
    fill_csr_kernel<<<(E + 255) / 256, 256, 0, stream>>>(src, dst, row_ptr, fill, col_src, E);

    // ---- Layer 1 ----
    dual_gemm_kernel<IN_DIM, HID_DIM><<<256, 256, 0, stream>>>(
        feat, Ws1, Wn1, b1, hs, t_bf, N);
    gather_mean128_kernel<<<(N * 64 + 255) / 256, 256, 0, stream>>>(
        t_bf, hs, row_ptr, col_src, h1, N);

    // ---- Layer 2 ----
    dual_gemm_kernel<HID_DIM, OUT_DIM><<<256, 256, 0, stream>>>(
        h1, Ws2, Wn2, b2, hs, t_bf, N);
    {
        int waves = (N + 1) / 2;
        gather_mean64_kernel<<<(waves * 64 + 255) / 256, 256, 0, stream>>>(
            t_bf, hs, row_ptr, col_src, h2_bf, N);
    }

    // ---- Edge dots ----
    {
        int total = 2 * E * 8;
        edge_dot_kernel<<<(total + 255) / 256, 256, 0, stream>>>(
            h2_bf, src, dst, nsrc, ndst, (float*)d_out, E);
    }
}

// Round 4
// 276.606 us; speedup vs baseline: 12.0107x; 1.2105x over previous
//
#include <hip/hip_runtime.h>

#define IN_DIM 128
#define HID_DIM 128
#define OUT_DIM 64

typedef short bf16x8 __attribute__((ext_vector_type(8)));   // 8 bf16 (4 VGPRs)
typedef float f32x4  __attribute__((ext_vector_type(4)));   // 4 fp32 acc

// ---- bf16 helpers (storage-only; math in fp32) ----
__device__ inline float bflo(unsigned int u) { return __uint_as_float(u << 16); }
__device__ inline float bfhi(unsigned int u) { return __uint_as_float(u & 0xffff0000u); }
__device__ inline unsigned short f2bf(float f) {
    unsigned int b = __float_as_uint(f);
    return (unsigned short)((b + 0x7FFFu + ((b >> 16) & 1u)) >> 16);  // RNE
}
__device__ inline unsigned int pack2(float a, float b) {
    return (unsigned int)f2bf(a) | ((unsigned int)f2bf(b) << 16);
}

// ===========================================================================
// CSR build: histogram -> 3-kernel exclusive scan -> fill column (src) array
// ===========================================================================
__global__ void hist_kernel(const int* __restrict__ dst, int* __restrict__ cnt, int E) {
    int e = blockIdx.x * blockDim.x + threadIdx.x;
    if (e < E) atomicAdd(&cnt[dst[e]], 1);
}

__global__ void block_sums_kernel(const int* __restrict__ cnt, int* __restrict__ partial, int N) {
    __shared__ int s[256];
    int i = blockIdx.x * 256 + threadIdx.x;
    s[threadIdx.x] = (i < N) ? cnt[i] : 0;
    __syncthreads();
    for (int o = 128; o > 0; o >>= 1) {
        if (threadIdx.x < o) s[threadIdx.x] += s[threadIdx.x + o];
        __syncthreads();
    }
    if (threadIdx.x == 0) partial[blockIdx.x] = s[0];
}

__global__ void scan_partials_kernel(int* __restrict__ partial, int nB) {
    __shared__ int s[256];
    int v = (threadIdx.x < nB) ? partial[threadIdx.x] : 0;
    s[threadIdx.x] = v;
    __syncthreads();
    for (int o = 1; o < 256; o <<= 1) {
        int t = (threadIdx.x >= o) ? s[threadIdx.x - o] : 0;
        __syncthreads();
        s[threadIdx.x] += t;
        __syncthreads();
    }
    if (threadIdx.x < nB) partial[threadIdx.x] = s[threadIdx.x] - v;  // exclusive
}

__global__ void scan_chunks_kernel(const int* __restrict__ cnt, const int* __restrict__ partial,
                                   int* __restrict__ row_ptr, int N) {
    __shared__ int s[256];
    int i = blockIdx.x * 256 + threadIdx.x;
    int v = (i < N) ? cnt[i] : 0;
    s[threadIdx.x] = v;
    __syncthreads();
    for (int o = 1; o < 256; o <<= 1) {
        int t = (threadIdx.x >= o) ? s[threadIdx.x - o] : 0;
        __syncthreads();
        s[threadIdx.x] += t;
        __syncthreads();
    }
    int incl = s[threadIdx.x];
    int base = partial[blockIdx.x];
    if (i < N) row_ptr[i] = base + incl - v;
    if (i == N - 1) row_ptr[N] = base + incl;
}

__global__ void fill_csr_kernel(const int* __restrict__ src, const int* __restrict__ dst,
                                const int* __restrict__ row_ptr, int* __restrict__ fill,
                                int* __restrict__ col_src, int E) {
    int e = blockIdx.x * blockDim.x + threadIdx.x;
    if (e >= E) return;
    int t = dst[e];
    int p = row_ptr[t] + atomicAdd(&fill[t], 1);
    col_src[p] = src[e];
}

// ===========================================================================
// MFMA dual GEMM (bf16 in, fp32 acc):
//   hs[n][0:DOUT] = x[n]@Wself + b  (fp32 out)
//   t [n][0:DOUT] = x[n]@Wneigh    (bf16 out)
// Combined B = [Wself | Wneigh] : WCOLS = 2*DOUT. 4 waves, each owns a
// 64-node x (WCOLS/4)-col quadrant. Weights live in per-wave registers;
// A tile (64x128) staged fp32->bf16 in LDS with +8 pad (2-way bank, free).
// ===========================================================================
template<int DOUT>
__global__ __launch_bounds__(256) void mfma_dual_gemm_kernel(
        const float* __restrict__ x,
        const float* __restrict__ Wself,
        const float* __restrict__ Wneigh,
        const float* __restrict__ bias,
        float* __restrict__ hs,
        unsigned short* __restrict__ t,
        int N) {
    constexpr int K   = 128;
    constexpr int MT  = 64;          // node tile
    constexpr int WC  = 2 * DOUT;    // combined cols (256 / 128)
    constexpr int SL  = WC / 4;      // cols per wave (64 / 32)
    constexpr int TN  = SL / 16;     // col tiles per wave (4 / 2)
    constexpr int TM  = MT / 16;     // 4
    constexpr int KS  = K / 32;      // 4
    constexpr int LDA = K + 8;       // padded row stride (shorts)

    __shared__ unsigned short sA[MT][LDA];

    const int tid = threadIdx.x;
    const int w   = tid >> 6;
    const int l   = tid & 63;
    const int l16 = l & 15;
    const int lhi = l >> 4;

    // ---- stage weights into register fragments (once per block) ----
    bf16x8 breg[TN][KS];
    float  bval[TN];
    #pragma unroll
    for (int tn = 0; tn < TN; ++tn) {
        const int c = w * SL + tn * 16 + l16;           // combined col
        const bool self = (c < DOUT);
        const float* W = self ? &Wself[c] : &Wneigh[c - DOUT];
        bval[tn] = self ? bias[c] : 0.0f;
        #pragma unroll
        for (int ks = 0; ks < KS; ++ks) {
            const int k0 = ks * 32 + lhi * 8;
            bf16x8 f;
            #pragma unroll
            for (int j = 0; j < 8; ++j)
                f[j] = (short)f2bf(W[(size_t)(k0 + j) * DOUT]);
            breg[tn][ks] = f;
        }
    }

    for (int tile = blockIdx.x; tile * MT < N; tile += gridDim.x) {
        const int n0 = tile * MT;
        __syncthreads();
        // ---- stage A tile: 64 x 128 fp32 -> bf16 in LDS ----
        #pragma unroll
        for (int it = 0; it < 8; ++it) {
            int flat = it * 256 + tid;       // 0..2047
            int r  = flat >> 5;              // 32 float4 per row
            int c4 = flat & 31;
            float4 v = {0, 0, 0, 0};
            if (n0 + r < N) v = *(const float4*)&x[(size_t)(n0 + r) * K + c4 * 4];
            ushort4 p;
            p.x = f2bf(v.x); p.y = f2bf(v.y); p.z = f2bf(v.z); p.w = f2bf(v.w);
            *(ushort4*)&sA[r][c4 * 4] = p;
        }
        __syncthreads();

        f32x4 acc[TN][TM];
        #pragma unroll
        for (int tn = 0; tn < TN; ++tn)
            #pragma unroll
            for (int tm = 0; tm < TM; ++tm)
                acc[tn][tm] = (f32x4){0.0f, 0.0f, 0.0f, 0.0f};

        #pragma unroll
        for (int ks = 0; ks < KS; ++ks) {
            bf16x8 a[TM];
            #pragma unroll
            for (int tm = 0; tm < TM; ++tm)
                a[tm] = *(const bf16x8*)&sA[tm * 16 + l16][ks * 32 + lhi * 8];
            #pragma unroll
            for (int tn = 0; tn < TN; ++tn)
                #pragma unroll
                for (int tm = 0; tm < TM; ++tm)
                    acc[tn][tm] = __builtin_amdgcn_mfma_f32_16x16x32_bf16(
                        a[tm], breg[tn][ks], acc[tn][tm], 0, 0, 0);
        }

        // ---- epilogue: C/D layout col=lane&15, row=(lane>>4)*4+r ----
        #pragma unroll
        for (int tn = 0; tn < TN; ++tn) {
            const int c = w * SL + tn * 16 + l16;
            const bool self = (c < DOUT);
            const int cc = self ? c : c - DOUT;
            #pragma unroll
            for (int tm = 0; tm < TM; ++tm) {
                #pragma unroll
                for (int r = 0; r < 4; ++r) {
                    const int n = n0 + tm * 16 + lhi * 4 + r;
                    if (n < N) {
                        const float v = acc[tn][tm][r] + bval[tn];
                        if (self) hs[(size_t)n * DOUT + cc] = v;
                        else      t [(size_t)n * DOUT + cc] = f2bf(v);
                    }
                }
            }
        }
    }
}

// ===========================================================================
// Gather-mean layer 1 (D=128): one 64-lane wave per node, 4B (2 bf16) / lane.
// out (fp32) = relu(base + mean t[neighbors])
// ===========================================================================
__global__ void gather_mean128_kernel(const unsigned short* __restrict__ t,
                                      const float* __restrict__ base,
                                      const int* __restrict__ row_ptr,
                                      const int* __restrict__ col_src,
                                      float* __restrict__ out, int N) {
    int node = (blockIdx.x * blockDim.x + threadIdx.x) >> 6;
    int lane = threadIdx.x & 63;
    if (node >= N) return;
    const int beg = row_ptr[node], end = row_ptr[node + 1];
    const float rdeg = 1.0f / fmaxf((float)(end - beg), 1.0f);
    const int off = lane * 2;

    float a0x = 0, a0y = 0, a1x = 0, a1y = 0, a2x = 0, a2y = 0, a3x = 0, a3y = 0;
    int i = beg;
    for (; i + 4 <= end; i += 4) {
        int s0 = col_src[i], s1 = col_src[i + 1], s2 = col_src[i + 2], s3 = col_src[i + 3];
        unsigned int u0 = *(const unsigned int*)&t[(size_t)s0 * 128 + off];
        unsigned int u1 = *(const unsigned int*)&t[(size_t)s1 * 128 + off];
        unsigned int u2 = *(const unsigned int*)&t[(size_t)s2 * 128 + off];
        unsigned int u3 = *(const unsigned int*)&t[(size_t)s3 * 128 + off];
        a0x += bflo(u0); a0y += bfhi(u0);
        a1x += bflo(u1); a1y += bfhi(u1);
        a2x += bflo(u2); a2y += bfhi(u2);
        a3x += bflo(u3); a3y += bfhi(u3);
    }
    for (; i < end; ++i) {
        unsigned int u = *(const unsigned int*)&t[(size_t)col_src[i] * 128 + off];
        a0x += bflo(u); a0y += bfhi(u);
    }
    float ax = (a0x + a1x) + (a2x + a3x);
    float ay = (a0y + a1y) + (a2y + a3y);
    float2 b = *(const float2*)&base[(size_t)node * 128 + off];
    float ox = fmaxf(b.x + ax * rdeg, 0.0f);
    float oy = fmaxf(b.y + ay * rdeg, 0.0f);
    float2 o = {ox, oy};
    *(float2*)&out[(size_t)node * 128 + off] = o;
}

// ===========================================================================
// Gather-mean layer 2 (D=64): 32 lanes per node (2 nodes/wave), bf16 out.
// ===========================================================================
__global__ void gather_mean64_kernel(const unsigned short* __restrict__ t,
                                     const float* __restrict__ base,
                                     const int* __restrict__ row_ptr,
                                     const int* __restrict__ col_src,
                                     unsigned short* __restrict__ out, int N) {
    int tid  = blockIdx.x * blockDim.x + threadIdx.x;
    int node = (tid >> 6) * 2 + ((tid >> 5) & 1);
    int m    = tid & 31;
    if (node >= N) return;
    const int beg = row_ptr[node], end = row_ptr[node + 1];
    const float rdeg = 1.0f / fmaxf((float)(end - beg), 1.0f);
    const int off = m * 2;

    float a0x = 0, a0y = 0, a1x = 0, a1y = 0, a2x = 0, a2y = 0, a3x = 0, a3y = 0;
    int i = beg;
    for (; i + 4 <= end; i += 4) {
        int s0 = col_src[i], s1 = col_src[i + 1], s2 = col_src[i + 2], s3 = col_src[i + 3];
        unsigned int u0 = *(const unsigned int*)&t[(size_t)s0 * 64 + off];
        unsigned int u1 = *(const unsigned int*)&t[(size_t)s1 * 64 + off];
        unsigned int u2 = *(const unsigned int*)&t[(size_t)s2 * 64 + off];
        unsigned int u3 = *(const unsigned int*)&t[(size_t)s3 * 64 + off];
        a0x += bflo(u0); a0y += bfhi(u0);
        a1x += bflo(u1); a1y += bfhi(u1);
        a2x += bflo(u2); a2y += bfhi(u2);
        a3x += bflo(u3); a3y += bfhi(u3);
    }
    for (; i < end; ++i) {
        unsigned int u = *(const unsigned int*)&t[(size_t)col_src[i] * 64 + off];
        a0x += bflo(u); a0y += bfhi(u);
    }
    float ax = (a0x + a1x) + (a2x + a3x);
    float ay = (a0y + a1y) + (a2y + a3y);
    float2 b = *(const float2*)&base[(size_t)node * 64 + off];
    *(unsigned int*)&out[(size_t)node * 64 + off] = pack2(b.x + ax * rdeg, b.y + ay * rdeg);
}

// ===========================================================================
// Edge dot on bf16 h (D=64, 128B rows): 8 lanes/edge, uint4 (8 bf16) loads.
// ===========================================================================
__global__ void edge_dot_kernel(const unsigned short* __restrict__ h,
                                const int* __restrict__ src,
                                const int* __restrict__ dst,
                                const int* __restrict__ nsrc,
                                const int* __restrict__ ndst,
                                float* __restrict__ out,
                                int E) {
    int tid = blockIdx.x * blockDim.x + threadIdx.x;
    int eg = tid >> 3;
    int l  = tid & 7;
    if (eg >= 2 * E) return;
    int s, t;
    if (eg < E) { s = src[eg];      t = dst[eg]; }
    else        { s = nsrc[eg - E]; t = ndst[eg - E]; }
    const uint4 a = *reinterpret_cast<const uint4*>(&h[(size_t)s * OUT_DIM + l * 8]);
    const uint4 b = *reinterpret_cast<const uint4*>(&h[(size_t)t * OUT_DIM + l * 8]);
    float v = bflo(a.x) * bflo(b.x) + bfhi(a.x) * bfhi(b.x)
            + bflo(a.y) * bflo(b.y) + bfhi(a.y) * bfhi(b.y)
            + bflo(a.z) * bflo(b.z) + bfhi(a.z) * bfhi(b.z)
            + bflo(a.w) * bflo(b.w) + bfhi(a.w) * bfhi(b.w);
    v += __shfl_xor(v, 4, 8);
    v += __shfl_xor(v, 2, 8);
    v += __shfl_xor(v, 1, 8);
    if (l == 0) out[eg] = v;
}

extern "C" void kernel_launch(void* const* d_in, const int* in_sizes, int n_in,
                              void* d_out, int out_size, void* d_ws, size_t ws_size,
                              hipStream_t stream) {
    const float* feat = (const float*)d_in[0];
    const float* Ws1  = (const float*)d_in[1];
    const float* Wn1  = (const float*)d_in[2];
    const float* b1   = (const float*)d_in[3];
    const float* Ws2  = (const float*)d_in[4];
    const float* Wn2  = (const float*)d_in[5];
    const float* b2   = (const float*)d_in[6];
    const int* src  = (const int*)d_in[7];
    const int* dst  = (const int*)d_in[8];
    const int* nsrc = (const int*)d_in[9];
    const int* ndst = (const int*)d_in[10];
    const int E = in_sizes[7];
    const int N = in_sizes[0] / IN_DIM;
    const int NB = (N + 255) / 256;
    const int NT = (N + 63) / 64;    // MFMA node tiles

    // ---- workspace layout ----
    int* wsi     = (int*)d_ws;
    int* cnt     = wsi;                  // N
    int* fill    = cnt + N;              // N
    int* row_ptr = fill + N;             // N+1
    int* partial = row_ptr + N + 1;      // 256
    int* col_src = partial + 256;        // E
    size_t int_count = (size_t)(3 * N + 1 + 256) + (size_t)E;
    int_count = (int_count + 3) & ~(size_t)3;
    unsigned short* t_bf = (unsigned short*)(wsi + int_count);       // N*128 bf16 (t1 / t2)
    float* hs = (float*)(t_bf + (size_t)N * HID_DIM);                // N*128 fp32 (hs1 / hs2)
    float* h1 = hs + (size_t)N * HID_DIM;                            // N*128 fp32
    unsigned short* h2_bf = (unsigned short*)(h1 + (size_t)N * HID_DIM);  // N*64 bf16

    // ---- CSR build ----
    hipMemsetAsync(cnt, 0, sizeof(int) * 2 * (size_t)N, stream);
    hist_kernel<<<(E + 255) / 256, 256, 0, stream>>>(dst, cnt, E);
    block_sums_kernel<<<NB, 256, 0, stream>>>(cnt, partial, N);
    scan_partials_kernel<<<1, 256, 0, stream>>>(partial, NB);
    scan_chunks_kernel<<<NB, 256, 0, stream>>>(cnt, partial, row_ptr, N);
    fill_csr_kernel<<<(E + 255) / 256, 256, 0, stream>>>(src, dst, row_ptr, fill, col_src, E);

    // ---- Layer 1: MFMA dual GEMM + gather-mean(+ReLU) ----
    mfma_dual_gemm_kernel<HID_DIM><<<NT, 256, 0, stream>>>(
        feat, Ws1, Wn1, b1, hs, t_bf, N);
    gather_mean128_kernel<<<(N * 64 + 255) / 256, 256, 0, stream>>>(
        t_bf, hs, row_ptr, col_src, h1, N);

    // ---- Layer 2: MFMA dual GEMM + gather-mean ----
    mfma_dual_gemm_kernel<OUT_DIM><<<NT, 256, 0, stream>>>(
        h1, Ws2, Wn2, b2, hs, t_bf, N);
    {
        int waves = (N + 1) / 2;
        gather_mean64_kernel<<<(waves * 64 + 255) / 256, 256, 0, stream>>>(
            t_bf, hs, row_ptr, col_src, h2_bf, N);
    }

    // ---- Edge dots ----
    {
        int total = 2 * E * 8;
        edge_dot_kernel<<<(total + 255) / 256, 256, 0, stream>>>(
            h2_bf, src, dst, nsrc, ndst, (float*)d_out, E);
    }
}

// Round 5
// 235.125 us; speedup vs baseline: 14.1296x; 1.1764x over previous
//
#include <hip/hip_runtime.h>

#define IN_DIM 128
#define HID_DIM 128
#define OUT_DIM 64

typedef short bf16x8 __attribute__((ext_vector_type(8)));   // 8 bf16 (4 VGPRs)
typedef float f32x4  __attribute__((ext_vector_type(4)));   // 4 fp32 acc

// ---- bf16 helpers (storage-only; math in fp32) ----
__device__ inline float bflo(unsigned int u) { return __uint_as_float(u << 16); }
__device__ inline float bfhi(unsigned int u) { return __uint_as_float(u & 0xffff0000u); }
__device__ inline unsigned short f2bf(float f) {
    unsigned int b = __float_as_uint(f);
    return (unsigned short)((b + 0x7FFFu + ((b >> 16) & 1u)) >> 16);  // RNE
}
__device__ inline unsigned int pack2(float a, float b) {
    return (unsigned int)f2bf(a) | ((unsigned int)f2bf(b) << 16);
}

// ===========================================================================
// CSR build step 1: histogram + per-edge rank (atomic return value).
// rank[e] is e's index among same-dst edges -> fill needs no atomics later.
// ===========================================================================
__global__ void hist_rank_kernel(const int* __restrict__ dst, int* __restrict__ cnt,
                                 int* __restrict__ rank, int E) {
    int e = blockIdx.x * blockDim.x + threadIdx.x;
    if (e < E) rank[e] = atomicAdd(&cnt[dst[e]], 1);
}

__global__ void block_sums_kernel(const int* __restrict__ cnt, int* __restrict__ partial, int N) {
    __shared__ int s[256];
    int i = blockIdx.x * 256 + threadIdx.x;
    s[threadIdx.x] = (i < N) ? cnt[i] : 0;
    __syncthreads();
    for (int o = 128; o > 0; o >>= 1) {
        if (threadIdx.x < o) s[threadIdx.x] += s[threadIdx.x + o];
        __syncthreads();
    }
    if (threadIdx.x == 0) partial[blockIdx.x] = s[0];
}

__global__ void scan_partials_kernel(int* __restrict__ partial, int nB) {
    __shared__ int s[256];
    int v = (threadIdx.x < nB) ? partial[threadIdx.x] : 0;
    s[threadIdx.x] = v;
    __syncthreads();
    for (int o = 1; o < 256; o <<= 1) {
        int t = (threadIdx.x >= o) ? s[threadIdx.x - o] : 0;
        __syncthreads();
        s[threadIdx.x] += t;
        __syncthreads();
    }
    if (threadIdx.x < nB) partial[threadIdx.x] = s[threadIdx.x] - v;  // exclusive
}

__global__ void scan_chunks_kernel(const int* __restrict__ cnt, const int* __restrict__ partial,
                                   int* __restrict__ row_ptr, int N) {
    __shared__ int s[256];
    int i = blockIdx.x * 256 + threadIdx.x;
    int v = (i < N) ? cnt[i] : 0;
    s[threadIdx.x] = v;
    __syncthreads();
    for (int o = 1; o < 256; o <<= 1) {
        int t = (threadIdx.x >= o) ? s[threadIdx.x - o] : 0;
        __syncthreads();
        s[threadIdx.x] += t;
        __syncthreads();
    }
    int incl = s[threadIdx.x];
    int base = partial[blockIdx.x];
    if (i < N) row_ptr[i] = base + incl - v;
    if (i == N - 1) row_ptr[N] = base + incl;
}

// ===========================================================================
// Fused kernel: blocks [0, NT) run layer-1 MFMA dual GEMM tiles; blocks
// [NT, NT+FB) run the non-atomic CSR scatter (col_src[row_ptr[d]+rank[e]]=src[e]).
// The latency-bound scatter overlaps the compute-bound GEMM in one dispatch.
//
// GEMM: hs[n] = x[n]@Wself + b (fp32) ; t[n] = x[n]@Wneigh (bf16).
// Combined B = [Wself | Wneigh]; 4 waves x 64-node x (2*DOUT/4)-col quadrants;
// weights in registers, A tile staged fp32->bf16 in LDS (+8 pad).
// ===========================================================================
template<int DOUT>
__global__ __launch_bounds__(256) void gemm_fill_kernel(
        const float* __restrict__ x,
        const float* __restrict__ Wself,
        const float* __restrict__ Wneigh,
        const float* __restrict__ bias,
        float* __restrict__ hs,
        unsigned short* __restrict__ t,
        int N, int NT,
        const int* __restrict__ src,
        const int* __restrict__ dst,
        const int* __restrict__ row_ptr,
        const int* __restrict__ rank,
        int* __restrict__ col_src,
        int E) {
    constexpr int K   = 128;
    constexpr int MT  = 64;
    constexpr int WC  = 2 * DOUT;
    constexpr int SL  = WC / 4;
    constexpr int TN  = SL / 16;
    constexpr int TM  = MT / 16;
    constexpr int KS  = K / 32;
    constexpr int LDA = K + 8;

    __shared__ unsigned short sA[MT][LDA];

    const int tid = threadIdx.x;

    if ((int)blockIdx.x >= NT) {
        // ---------------- CSR scatter part (no atomics) ----------------
        int base = ((int)blockIdx.x - NT) * 1024;
        #pragma unroll
        for (int k = 0; k < 4; ++k) {
            int e = base + k * 256 + tid;
            if (e < E) {
                int d = dst[e];
                col_src[row_ptr[d] + rank[e]] = src[e];
            }
        }
        return;
    }

    // ---------------- GEMM part ----------------
    const int w   = tid >> 6;
    const int l   = tid & 63;
    const int l16 = l & 15;
    const int lhi = l >> 4;

    bf16x8 breg[TN][KS];
    float  bval[TN];
    #pragma unroll
    for (int tn = 0; tn < TN; ++tn) {
        const int c = w * SL + tn * 16 + l16;
        const bool self = (c < DOUT);
        const float* W = self ? &Wself[c] : &Wneigh[c - DOUT];
        bval[tn] = self ? bias[c] : 0.0f;
        #pragma unroll
        for (int ks = 0; ks < KS; ++ks) {
            const int k0 = ks * 32 + lhi * 8;
            bf16x8 f;
            #pragma unroll
            for (int j = 0; j < 8; ++j)
                f[j] = (short)f2bf(W[(size_t)(k0 + j) * DOUT]);
            breg[tn][ks] = f;
        }
    }

    const int n0 = (int)blockIdx.x * MT;
    // ---- stage A tile: 64 x 128 fp32 -> bf16 in LDS ----
    #pragma unroll
    for (int it = 0; it < 8; ++it) {
        int flat = it * 256 + tid;
        int r  = flat >> 5;
        int c4 = flat & 31;
        float4 v = {0, 0, 0, 0};
        if (n0 + r < N) v = *(const float4*)&x[(size_t)(n0 + r) * K + c4 * 4];
        ushort4 p;
        p.x = f2bf(v.x); p.y = f2bf(v.y); p.z = f2bf(v.z); p.w = f2bf(v.w);
        *(ushort4*)&sA[r][c4 * 4] = p;
    }
    __syncthreads();

    f32x4 acc[TN][TM];
    #pragma unroll
    for (int tn = 0; tn < TN; ++tn)
        #pragma unroll
        for (int tm = 0; tm < TM; ++tm)
            acc[tn][tm] = (f32x4){0.0f, 0.0f, 0.0f, 0.0f};

    #pragma unroll
    for (int ks = 0; ks < KS; ++ks) {
        bf16x8 a[TM];
        #pragma unroll
        for (int tm = 0; tm < TM; ++tm)
            a[tm] = *(const bf16x8*)&sA[tm * 16 + l16][ks * 32 + lhi * 8];
        #pragma unroll
        for (int tn = 0; tn < TN; ++tn)
            #pragma unroll
            for (int tm = 0; tm < TM; ++tm)
                acc[tn][tm] = __builtin_amdgcn_mfma_f32_16x16x32_bf16(
                    a[tm], breg[tn][ks], acc[tn][tm], 0, 0, 0);
    }

    // ---- epilogue: C/D layout col=lane&15, row=(lane>>4)*4+r ----
    #pragma unroll
    for (int tn = 0; tn < TN; ++tn) {
        const int c = w * SL + tn * 16 + l16;
        const bool self = (c < DOUT);
        const int cc = self ? c : c - DOUT;
        #pragma unroll
        for (int tm = 0; tm < TM; ++tm) {
            #pragma unroll
            for (int r = 0; r < 4; ++r) {
                const int n = n0 + tm * 16 + lhi * 4 + r;
                if (n < N) {
                    const float v = acc[tn][tm][r] + bval[tn];
                    if (self) hs[(size_t)n * DOUT + cc] = v;
                    else      t [(size_t)n * DOUT + cc] = f2bf(v);
                }
            }
        }
    }
}

// ===========================================================================
// Plain MFMA dual GEMM (layer 2; no fused scatter).
// ===========================================================================
template<int DOUT>
__global__ __launch_bounds__(256) void mfma_dual_gemm_kernel(
        const float* __restrict__ x,
        const float* __restrict__ Wself,
        const float* __restrict__ Wneigh,
        const float* __restrict__ bias,
        float* __restrict__ hs,
        unsigned short* __restrict__ t,
        int N) {
    constexpr int K   = 128;
    constexpr int MT  = 64;
    constexpr int WC  = 2 * DOUT;
    constexpr int SL  = WC / 4;
    constexpr int TN  = SL / 16;
    constexpr int TM  = MT / 16;
    constexpr int KS  = K / 32;
    constexpr int LDA = K + 8;

    __shared__ unsigned short sA[MT][LDA];

    const int tid = threadIdx.x;
    const int w   = tid >> 6;
    const int l   = tid & 63;
    const int l16 = l & 15;
    const int lhi = l >> 4;

    bf16x8 breg[TN][KS];
    float  bval[TN];
    #pragma unroll
    for (int tn = 0; tn < TN; ++tn) {
        const int c = w * SL + tn * 16 + l16;
        const bool self = (c < DOUT);
        const float* W = self ? &Wself[c] : &Wneigh[c - DOUT];
        bval[tn] = self ? bias[c] : 0.0f;
        #pragma unroll
        for (int ks = 0; ks < KS; ++ks) {
            const int k0 = ks * 32 + lhi * 8;
            bf16x8 f;
            #pragma unroll
            for (int j = 0; j < 8; ++j)
                f[j] = (short)f2bf(W[(size_t)(k0 + j) * DOUT]);
            breg[tn][ks] = f;
        }
    }

    const int n0 = (int)blockIdx.x * MT;
    #pragma unroll
    for (int it = 0; it < 8; ++it) {
        int flat = it * 256 + tid;
        int r  = flat >> 5;
        int c4 = flat & 31;
        float4 v = {0, 0, 0, 0};
        if (n0 + r < N) v = *(const float4*)&x[(size_t)(n0 + r) * K + c4 * 4];
        ushort4 p;
        p.x = f2bf(v.x); p.y = f2bf(v.y); p.z = f2bf(v.z); p.w = f2bf(v.w);
        *(ushort4*)&sA[r][c4 * 4] = p;
    }
    __syncthreads();

    f32x4 acc[TN][TM];
    #pragma unroll
    for (int tn = 0; tn < TN; ++tn)
        #pragma unroll
        for (int tm = 0; tm < TM; ++tm)
            acc[tn][tm] = (f32x4){0.0f, 0.0f, 0.0f, 0.0f};

    #pragma unroll
    for (int ks = 0; ks < KS; ++ks) {
        bf16x8 a[TM];
        #pragma unroll
        for (int tm = 0; tm < TM; ++tm)
            a[tm] = *(const bf16x8*)&sA[tm * 16 + l16][ks * 32 + lhi * 8];
        #pragma unroll
        for (int tn = 0; tn < TN; ++tn)
            #pragma unroll
            for (int tm = 0; tm < TM; ++tm)
                acc[tn][tm] = __builtin_amdgcn_mfma_f32_16x16x32_bf16(
                    a[tm], breg[tn][ks], acc[tn][tm], 0, 0, 0);
    }

    #pragma unroll
    for (int tn = 0; tn < TN; ++tn) {
        const int c = w * SL + tn * 16 + l16;
        const bool self = (c < DOUT);
        const int cc = self ? c : c - DOUT;
        #pragma unroll
        for (int tm = 0; tm < TM; ++tm) {
            #pragma unroll
            for (int r = 0; r < 4; ++r) {
                const int n = n0 + tm * 16 + lhi * 4 + r;
                if (n < N) {
                    const float v = acc[tn][tm][r] + bval[tn];
                    if (self) hs[(size_t)n * DOUT + cc] = v;
                    else      t [(size_t)n * DOUT + cc] = f2bf(v);
                }
            }
        }
    }
}

// ===========================================================================
// Gather-mean layer 1 (D=128): one 64-lane wave per node, 4B (2 bf16) / lane.
// out (fp32) = relu(base + mean t[neighbors])
// ===========================================================================
__global__ void gather_mean128_kernel(const unsigned short* __restrict__ t,
                                      const float* __restrict__ base,
                                      const int* __restrict__ row_ptr,
                                      const int* __restrict__ col_src,
                                      float* __restrict__ out, int N) {
    int node = (blockIdx.x * blockDim.x + threadIdx.x) >> 6;
    int lane = threadIdx.x & 63;
    if (node >= N) return;
    const int beg = row_ptr[node], end = row_ptr[node + 1];
    const float rdeg = 1.0f / fmaxf((float)(end - beg), 1.0f);
    const int off = lane * 2;

    float a0x = 0, a0y = 0, a1x = 0, a1y = 0, a2x = 0, a2y = 0, a3x = 0, a3y = 0;
    int i = beg;
    for (; i + 4 <= end; i += 4) {
        int s0 = col_src[i], s1 = col_src[i + 1], s2 = col_src[i + 2], s3 = col_src[i + 3];
        unsigned int u0 = *(const unsigned int*)&t[(size_t)s0 * 128 + off];
        unsigned int u1 = *(const unsigned int*)&t[(size_t)s1 * 128 + off];
        unsigned int u2 = *(const unsigned int*)&t[(size_t)s2 * 128 + off];
        unsigned int u3 = *(const unsigned int*)&t[(size_t)s3 * 128 + off];
        a0x += bflo(u0); a0y += bfhi(u0);
        a1x += bflo(u1); a1y += bfhi(u1);
        a2x += bflo(u2); a2y += bfhi(u2);
        a3x += bflo(u3); a3y += bfhi(u3);
    }
    for (; i < end; ++i) {
        unsigned int u = *(const unsigned int*)&t[(size_t)col_src[i] * 128 + off];
        a0x += bflo(u); a0y += bfhi(u);
    }
    float ax = (a0x + a1x) + (a2x + a3x);
    float ay = (a0y + a1y) + (a2y + a3y);
    float2 b = *(const float2*)&base[(size_t)node * 128 + off];
    float ox = fmaxf(b.x + ax * rdeg, 0.0f);
    float oy = fmaxf(b.y + ay * rdeg, 0.0f);
    float2 o = {ox, oy};
    *(float2*)&out[(size_t)node * 128 + off] = o;
}

// ===========================================================================
// Gather-mean layer 2 (D=64): 32 lanes per node (2 nodes/wave), bf16 out.
// ===========================================================================
__global__ void gather_mean64_kernel(const unsigned short* __restrict__ t,
                                     const float* __restrict__ base,
                                     const int* __restrict__ row_ptr,
                                     const int* __restrict__ col_src,
                                     unsigned short* __restrict__ out, int N) {
    int tid  = blockIdx.x * blockDim.x + threadIdx.x;
    int node = (tid >> 6) * 2 + ((tid >> 5) & 1);
    int m    = tid & 31;
    if (node >= N) return;
    const int beg = row_ptr[node], end = row_ptr[node + 1];
    const float rdeg = 1.0f / fmaxf((float)(end - beg), 1.0f);
    const int off = m * 2;

    float a0x = 0, a0y = 0, a1x = 0, a1y = 0, a2x = 0, a2y = 0, a3x = 0, a3y = 0;
    int i = beg;
    for (; i + 4 <= end; i += 4) {
        int s0 = col_src[i], s1 = col_src[i + 1], s2 = col_src[i + 2], s3 = col_src[i + 3];
        unsigned int u0 = *(const unsigned int*)&t[(size_t)s0 * 64 + off];
        unsigned int u1 = *(const unsigned int*)&t[(size_t)s1 * 64 + off];
        unsigned int u2 = *(const unsigned int*)&t[(size_t)s2 * 64 + off];
        unsigned int u3 = *(const unsigned int*)&t[(size_t)s3 * 64 + off];
        a0x += bflo(u0); a0y += bfhi(u0);
        a1x += bflo(u1); a1y += bfhi(u1);
        a2x += bflo(u2); a2y += bfhi(u2);
        a3x += bflo(u3); a3y += bfhi(u3);
    }
    for (; i < end; ++i) {
        unsigned int u = *(const unsigned int*)&t[(size_t)col_src[i] * 64 + off];
        a0x += bflo(u); a0y += bfhi(u);
    }
    float ax = (a0x + a1x) + (a2x + a3x);
    float ay = (a0y + a1y) + (a2y + a3y);
    float2 b = *(const float2*)&base[(size_t)node * 64 + off];
    *(unsigned int*)&out[(size_t)node * 64 + off] = pack2(b.x + ax * rdeg, b.y + ay * rdeg);
}

// ===========================================================================
// Edge dot on bf16 h (D=64, 128B rows): 8 lanes/edge, uint4 (8 bf16) loads.
// ===========================================================================
__global__ void edge_dot_kernel(const unsigned short* __restrict__ h,
                                const int* __restrict__ src,
                                const int* __restrict__ dst,
                                const int* __restrict__ nsrc,
                                const int* __restrict__ ndst,
                                float* __restrict__ out,
                                int E) {
    int tid = blockIdx.x * blockDim.x + threadIdx.x;
    int eg = tid >> 3;
    int l  = tid & 7;
    if (eg >= 2 * E) return;
    int s, t;
    if (eg < E) { s = src[eg];      t = dst[eg]; }
    else        { s = nsrc[eg - E]; t = ndst[eg - E]; }
    const uint4 a = *reinterpret_cast<const uint4*>(&h[(size_t)s * OUT_DIM + l * 8]);
    const uint4 b = *reinterpret_cast<const uint4*>(&h[(size_t)t * OUT_DIM + l * 8]);
    float v = bflo(a.x) * bflo(b.x) + bfhi(a.x) * bfhi(b.x)
            + bflo(a.y) * bflo(b.y) + bfhi(a.y) * bfhi(b.y)
            + bflo(a.z) * bflo(b.z) + bfhi(a.z) * bfhi(b.z)
            + bflo(a.w) * bflo(b.w) + bfhi(a.w) * bfhi(b.w);
    v += __shfl_xor(v, 4, 8);
    v += __shfl_xor(v, 2, 8);
    v += __shfl_xor(v, 1, 8);
    if (l == 0) out[eg] = v;
}

extern "C" void kernel_launch(void* const* d_in, const int* in_sizes, int n_in,
                              void* d_out, int out_size, void* d_ws, size_t ws_size,
                              hipStream_t stream) {
    const float* feat = (const float*)d_in[0];
    const float* Ws1  = (const float*)d_in[1];
    const float* Wn1  = (const float*)d_in[2];
    const float* b1   = (const float*)d_in[3];
    const float* Ws2  = (const float*)d_in[4];
    const float* Wn2  = (const float*)d_in[5];
    const float* b2   = (const float*)d_in[6];
    const int* src  = (const int*)d_in[7];
    const int* dst  = (const int*)d_in[8];
    const int* nsrc = (const int*)d_in[9];
    const int* ndst = (const int*)d_in[10];
    const int E = in_sizes[7];
    const int N = in_sizes[0] / IN_DIM;
    const int NB = (N + 255) / 256;
    const int NT = (N + 63) / 64;           // MFMA node tiles
    const int FB = (E + 1023) / 1024;       // scatter blocks (4 edges/thread)

    // ---- workspace layout ----
    int* wsi     = (int*)d_ws;
    int* cnt     = wsi;                  // N
    int* row_ptr = cnt + N;              // N+1
    int* partial = row_ptr + N + 1;      // 256
    int* col_src = partial + 256;        // E
    int* rank    = col_src + E;          // E
    size_t int_count = (size_t)(2 * N + 1 + 256) + 2 * (size_t)E;
    int_count = (int_count + 3) & ~(size_t)3;
    unsigned short* t_bf = (unsigned short*)(wsi + int_count);       // N*128 bf16 (t1 / t2)
    float* hs = (float*)(t_bf + (size_t)N * HID_DIM);                // N*128 fp32 (hs1 / hs2)
    float* h1 = hs + (size_t)N * HID_DIM;                            // N*128 fp32
    unsigned short* h2_bf = (unsigned short*)(h1 + (size_t)N * HID_DIM);  // N*64 bf16

    // ---- CSR build: hist(+rank) -> scan ----
    hipMemsetAsync(cnt, 0, sizeof(int) * (size_t)N, stream);
    hist_rank_kernel<<<(E + 255) / 256, 256, 0, stream>>>(dst, cnt, rank, E);
    block_sums_kernel<<<NB, 256, 0, stream>>>(cnt, partial, N);
    scan_partials_kernel<<<1, 256, 0, stream>>>(partial, NB);
    scan_chunks_kernel<<<NB, 256, 0, stream>>>(cnt, partial, row_ptr, N);

    // ---- Layer 1 GEMM fused with non-atomic CSR scatter ----
    gemm_fill_kernel<HID_DIM><<<NT + FB, 256, 0, stream>>>(
        feat, Ws1, Wn1, b1, hs, t_bf, N, NT,
        src, dst, row_ptr, rank, col_src, E);
    gather_mean128_kernel<<<(N * 64 + 255) / 256, 256, 0, stream>>>(
        t_bf, hs, row_ptr, col_src, h1, N);

    // ---- Layer 2 ----
    mfma_dual_gemm_kernel<OUT_DIM><<<NT, 256, 0, stream>>>(
        h1, Ws2, Wn2, b2, hs, t_bf, N);
    {
        int waves = (N + 1) / 2;
        gather_mean64_kernel<<<(waves * 64 + 255) / 256, 256, 0, stream>>>(
            t_bf, hs, row_ptr, col_src, h2_bf, N);
    }

    // ---- Edge dots ----
    {
        int total = 2 * E * 8;
        edge_dot_kernel<<<(total + 255) / 256, 256, 0, stream>>>(
            h2_bf, src, dst, nsrc, ndst, (float*)d_out, E);
    }
}